// Round 3
// baseline (435.023 us; speedup 1.0000x reference)
//
#include <hip/hip_runtime.h>
#include <hip/hip_bf16.h>

typedef __bf16 bf16x4 __attribute__((ext_vector_type(4)));
typedef __bf16 bf16x8 __attribute__((ext_vector_type(8)));
typedef float floatx4 __attribute__((ext_vector_type(4)));

#define GLD16(gp, lp) __builtin_amdgcn_global_load_lds(                      \
    (const __attribute__((address_space(1))) void*)(gp),                     \
    (__attribute__((address_space(3))) void*)(lp), 16, 0, 0)

constexpr int Mdim = 16384;   // B*S
constexpr int Ndim = 3072;    // 3*D
constexpr int Kdim = 1024;    // D

static __device__ __forceinline__ bf16x8 cvt8(floatx4 lo, floatx4 hi) {
    bf16x8 r;
#pragma unroll
    for (int e = 0; e < 4; ++e) { r[e] = (__bf16)lo[e]; r[e + 4] = (__bf16)hi[e]; }
    return r;
}

// ===========================================================================
// FAST PATH (requires ws_size >= 40 MB)
// ===========================================================================

// --- prep 1: W_eff = W_qkv + LoRA fold, fp32 accumulate -> bf16 ------------
__global__ __launch_bounds__(256) void build_weff(
    const float* __restrict__ Wqkv,   // 3072 x 1024
    const float* __restrict__ Waq,    // 16 x 1024
    const float* __restrict__ Wbq,    // 1024 x 16
    const float* __restrict__ Wav,    // 16 x 1024
    const float* __restrict__ Wbv,    // 1024 x 16
    __hip_bfloat16* __restrict__ Weff)
{
    const int idx = (blockIdx.x * 256 + threadIdx.x) * 4;  // e*1024 + d
    const int e = idx >> 10;
    const int d = idx & 1023;
    floatx4 v = *(const floatx4*)(Wqkv + idx);
    if (e < 1024) {
#pragma unroll
        for (int r = 0; r < 16; ++r) {
            const float wb = Wbq[e * 16 + r];
            floatx4 wa = *(const floatx4*)(Waq + r * 1024 + d);
#pragma unroll
            for (int q = 0; q < 4; ++q) v[q] += wb * wa[q];
        }
    } else if (e >= 2048) {
        const int e2 = e - 2048;
#pragma unroll
        for (int r = 0; r < 16; ++r) {
            const float wb = Wbv[e2 * 16 + r];
            floatx4 wa = *(const floatx4*)(Wav + r * 1024 + d);
#pragma unroll
            for (int q = 0; q < 4; ++q) v[q] += wb * wa[q];
        }
    }
    bf16x4 o;
#pragma unroll
    for (int q = 0; q < 4; ++q) o[q] = (__bf16)v[q];
    *(bf16x4*)(Weff + idx) = o;
}

// --- prep 2: x fp32 -> bf16 -------------------------------------------------
__global__ __launch_bounds__(256) void cvt_x(
    const float* __restrict__ x, __hip_bfloat16* __restrict__ xb)
{
    const size_t idx = ((size_t)blockIdx.x * 256 + threadIdx.x) * 8;
    bf16x8 r = cvt8(*(const floatx4*)(x + idx), *(const floatx4*)(x + idx + 4));
    *(bf16x8*)(xb + idx) = r;
}

// --- main GEMM v4: persistent 512-block, 6 n-tiles/block, deferred epilogue -
// 128x128 tile, BK=64, dbuf LDS (64 KiB -> 2 blocks/CU). Keeps v3's verified
// swizzle + counted vmcnt. New: (a) nontemporal C stores (no L3 pollution),
// (b) each block sweeps 6 n-tiles at fixed m0 (A-panel L2 reuse, no global
// round boundaries), (c) tile-T epilogue deferred: acc snapshot + 4x16-store
// chunks issued inside tile T+1's first 4 K-iterations, overlapping MFMA.
// vmcnt table derived from exact in-order VMEM queue contents (see notes).
__global__ __launch_bounds__(256, 2) void gemm_bf16_v4(
    const __hip_bfloat16* __restrict__ A,     // M x K bf16
    const __hip_bfloat16* __restrict__ Bw,    // N x K bf16 (W_eff)
    const float* __restrict__ bias,           // N fp32
    float* __restrict__ C)                    // M x N fp32
{
    constexpr int NT  = Kdim / 64;   // 16 K-tiles per output tile
    constexpr int TPB = 6;           // output tiles per block (n-sweep)
    __shared__ __hip_bfloat16 lds[2][2][128 * 64];   // 64 KiB

    const int t    = threadIdx.x;
    const int wave = t >> 6;
    const int lane = t & 63;
    const int wm   = wave >> 1;       // 2x2 wave grid, 64x64 output each
    const int wn   = wave & 1;

    // 512 blocks, XCD-bijective: xcd gets 64 contiguous bids = 16 m-rows.
    const int bid = (blockIdx.x & 7) * 64 + (blockIdx.x >> 3);
    const int m0  = (bid >> 2) * 128;         // 128 m-rows
    const int ng  = (bid & 3) * TPB;          // first of 6 consecutive n-tiles

    // staging geometry (v3-verified): linear LDS dest, pre-swizzled global col
    const int srow0 = t >> 3;                              // 0..31
    const int scb_s = ((t & 7) * 16) ^ ((srow0 & 7) << 4); // swizzled src col-byte
    const __hip_bfloat16* Agb = A  + (size_t)(m0 + srow0) * Kdim + (scb_s >> 1);
    const __hip_bfloat16* Bgb = Bw + (size_t)srow0 * Kdim + (scb_s >> 1);

#define STAGE(Bg_, kt_, nb_) do {                                              \
    const __hip_bfloat16* _ga = Agb + (kt_) * 64;                              \
    const __hip_bfloat16* _gb = (Bg_) + (kt_) * 64;                            \
    char* _la = (char*)&lds[nb_][0][0] + t * 16;                               \
    char* _lb = (char*)&lds[nb_][1][0] + t * 16;                               \
    GLD16(_ga,                      _la);                                      \
    GLD16(_ga + (size_t)32 * Kdim,  _la + 4096);                               \
    GLD16(_ga + (size_t)64 * Kdim,  _la + 8192);                               \
    GLD16(_ga + (size_t)96 * Kdim,  _la + 12288);                              \
    GLD16(_gb,                      _lb);                                      \
    GLD16(_gb + (size_t)32 * Kdim,  _lb + 4096);                               \
    GLD16(_gb + (size_t)64 * Kdim,  _lb + 8192);                               \
    GLD16(_gb + (size_t)96 * Kdim,  _lb + 12288);                              \
} while (0)

    // fragment-read geometry (v3-verified, bank-conflict-free)
    const int fm   = lane & 15;
    const int fk2  = (lane >> 4) * 16;
    const int fxor = (fm & 7) << 4;
    const int cbs0 = fk2 ^ fxor;              // k 0..31
    const int cbs1 = (64 + fk2) ^ fxor;       // k 32..63
    const int cn   = lane & 15;
    const int cm   = (lane >> 4) * 4;

    floatx4 acc[4][4], accp[4][4];
#pragma unroll
    for (int i = 0; i < 4; ++i)
#pragma unroll
        for (int j = 0; j < 4; ++j)
            acc[i][j] = (floatx4){0.f, 0.f, 0.f, 0.f};

    int n0  = ng * 128;
    int n0p = n0;
    float bv[4];
    // bias preload for tile 0, pinned so it precedes L_0 in the VMEM queue
    __builtin_amdgcn_sched_barrier(0);
#pragma unroll
    for (int j = 0; j < 4; ++j) bv[j] = bias[n0 + wn * 64 + j * 16 + cn];
    __builtin_amdgcn_sched_barrier(0);

    const __hip_bfloat16* Bg = Bgb + ((size_t)ng * 128) * Kdim;
    STAGE(Bg, 0, 0);                           // prologue: tile0, kt0 -> buf0

#pragma unroll 1
    for (int tile = 0; tile < TPB; ++tile) {
        const __hip_bfloat16* Bgn = Bg + (size_t)128 * Kdim;   // next n-tile
#pragma unroll
        for (int kt = 0; kt < NT; ++kt) {
            const int nb = kt & 1;             // NT even -> pattern continuous
            // 1. stage next K-tile (possibly next output tile's kt=0)
            if (kt < NT - 1)           STAGE(Bg,  kt + 1, nb ^ 1);
            else if (tile + 1 < TPB)   STAGE(Bgn, 0,      nb ^ 1);
            // 2. deferred store chunk (compile-time kt index; uniform branch)
            if (tile > 0 && kt < 4) {
#pragma unroll
                for (int j = 0; j < 4; ++j) {
                    const size_t base = (size_t)(m0 + wm * 64 + kt * 16 + cm) * Ndim
                                      + (n0p + wn * 64 + j * 16 + cn);
#pragma unroll
                    for (int r = 0; r < 4; ++r)
                        __builtin_nontemporal_store(accp[kt][j][r],
                                                    &C[base + (size_t)r * Ndim]);
                }
            }
            // 3. counted wait: need this iter's stage loads retired.
            //    Queue-derived (in-order retire; count = ops younger than L_kt):
            //    tile0: [L][L'] -> 8.  tile>0: kt0: bv4+L'8+S0:16 = 28;
            //    kt1-3: S(16)+L'(8)+S(16) = 40; kt4: S3(16)+L'(8) = 24; else 8.
            if (kt == NT - 1 && tile == TPB - 1)
                asm volatile("s_waitcnt vmcnt(0)" ::: "memory");
            else if (tile == 0)
                asm volatile("s_waitcnt vmcnt(8)" ::: "memory");
            else if (kt == 0)
                asm volatile("s_waitcnt vmcnt(28)" ::: "memory");
            else if (kt <= 3)
                asm volatile("s_waitcnt vmcnt(40)" ::: "memory");
            else if (kt == 4)
                asm volatile("s_waitcnt vmcnt(24)" ::: "memory");
            else
                asm volatile("s_waitcnt vmcnt(8)" ::: "memory");
            __builtin_amdgcn_s_barrier();

            // 4. LDS -> frags -> MFMA
            const char* Ab = (const char*)&lds[nb][0][0];
            const char* Bb = (const char*)&lds[nb][1][0];
            bf16x8 aq[2][4], bq[2][4];
#pragma unroll
            for (int i = 0; i < 4; ++i) {
                aq[0][i] = *(const bf16x8*)(Ab + (wm * 64 + i * 16 + fm) * 128 + cbs0);
                aq[1][i] = *(const bf16x8*)(Ab + (wm * 64 + i * 16 + fm) * 128 + cbs1);
                bq[0][i] = *(const bf16x8*)(Bb + (wn * 64 + i * 16 + fm) * 128 + cbs0);
                bq[1][i] = *(const bf16x8*)(Bb + (wn * 64 + i * 16 + fm) * 128 + cbs1);
            }
            __builtin_amdgcn_s_setprio(1);
#pragma unroll
            for (int kk = 0; kk < 2; ++kk)
#pragma unroll
                for (int i = 0; i < 4; ++i)
#pragma unroll
                    for (int j = 0; j < 4; ++j)
                        acc[i][j] = __builtin_amdgcn_mfma_f32_16x16x32_bf16(
                            aq[kk][i], bq[kk][j], acc[i][j], 0, 0, 0);
            __builtin_amdgcn_s_setprio(0);
            __builtin_amdgcn_s_barrier();
        }
        if (tile + 1 < TPB) {
            // tile boundary: snapshot acc(+bias) for deferred stores, reset acc
#pragma unroll
            for (int i = 0; i < 4; ++i)
#pragma unroll
                for (int j = 0; j < 4; ++j) {
#pragma unroll
                    for (int r = 0; r < 4; ++r)
                        accp[i][j][r] = acc[i][j][r] + bv[j];
                    acc[i][j] = (floatx4){0.f, 0.f, 0.f, 0.f};
                }
            n0p = n0;
            n0 += 128;
            // next tile's bias, pinned: queue position after L_next, before L'
            __builtin_amdgcn_sched_barrier(0);
#pragma unroll
            for (int j = 0; j < 4; ++j) bv[j] = bias[n0 + wn * 64 + j * 16 + cn];
            __builtin_amdgcn_sched_barrier(0);
            Bg = Bgn;
        }
    }

    // final tile epilogue (nontemporal)
#pragma unroll
    for (int i = 0; i < 4; ++i) {
        const int m = m0 + wm * 64 + i * 16 + cm;
#pragma unroll
        for (int j = 0; j < 4; ++j) {
            const size_t base = (size_t)m * Ndim + (n0 + wn * 64 + j * 16 + cn);
#pragma unroll
            for (int r = 0; r < 4; ++r)
                __builtin_nontemporal_store(acc[i][j][r] + bv[j],
                                            &C[base + (size_t)r * Ndim]);
        }
    }
#undef STAGE
}

// ===========================================================================
// FALLBACK PATH (R2, proven): used only if ws_size < 40 MB
// ===========================================================================

__global__ __launch_bounds__(256, 2) void gemm_bias_f32(
    const float* __restrict__ A, const float* __restrict__ Bw,
    const float* __restrict__ bias, float* __restrict__ C)
{
    constexpr int TK = 32;
    __shared__ __hip_bfloat16 As[128 * TK];
    __shared__ __hip_bfloat16 Bs[128 * TK];

    const int t    = threadIdx.x;
    const int wave = t >> 6;
    const int lane = t & 63;
    const int bx   = blockIdx.x % (Ndim / 128);
    const int by   = blockIdx.x / (Ndim / 128);
    const int m0   = by * 128;
    const int n0   = bx * 128;
    const int wm   = wave >> 1;
    const int wn   = wave & 1;
    const int srow = wave * 16 + (lane >> 2);
    const int scol = (lane & 3) * 8;

    const float* Ag0 = A  + (size_t)(m0 + srow) * Kdim + scol;
    const float* Ag1 = Ag0 + (size_t)64 * Kdim;
    const float* Bg0 = Bw + (size_t)(n0 + srow) * Kdim + scol;
    const float* Bg1 = Bg0 + (size_t)64 * Kdim;

    __hip_bfloat16* Al0 = &As[srow * TK + scol];
    __hip_bfloat16* Al1 = &As[(srow + 64) * TK + scol];
    __hip_bfloat16* Bl0 = &Bs[srow * TK + scol];
    __hip_bfloat16* Bl1 = &Bs[(srow + 64) * TK + scol];

    const int fm = lane & 15;
    const int fk = (lane >> 4) * 8;

    floatx4 acc[4][4];
#pragma unroll
    for (int i = 0; i < 4; ++i)
#pragma unroll
        for (int j = 0; j < 4; ++j)
            acc[i][j] = (floatx4){0.f, 0.f, 0.f, 0.f};

    for (int kt = 0; kt < Kdim; kt += TK) {
        bf16x8 a0 = cvt8(*(const floatx4*)(Ag0 + kt), *(const floatx4*)(Ag0 + kt + 4));
        bf16x8 a1 = cvt8(*(const floatx4*)(Ag1 + kt), *(const floatx4*)(Ag1 + kt + 4));
        bf16x8 b0 = cvt8(*(const floatx4*)(Bg0 + kt), *(const floatx4*)(Bg0 + kt + 4));
        bf16x8 b1 = cvt8(*(const floatx4*)(Bg1 + kt), *(const floatx4*)(Bg1 + kt + 4));
        __syncthreads();
        *(bf16x8*)Al0 = a0;
        *(bf16x8*)Al1 = a1;
        *(bf16x8*)Bl0 = b0;
        *(bf16x8*)Bl1 = b1;
        __syncthreads();

        bf16x8 af[4], bfr[4];
#pragma unroll
        for (int i = 0; i < 4; ++i) {
            af[i]  = *(const bf16x8*)&As[(wm * 64 + i * 16 + fm) * TK + fk];
            bfr[i] = *(const bf16x8*)&Bs[(wn * 64 + i * 16 + fm) * TK + fk];
        }
#pragma unroll
        for (int i = 0; i < 4; ++i)
#pragma unroll
            for (int j = 0; j < 4; ++j)
                acc[i][j] = __builtin_amdgcn_mfma_f32_16x16x32_bf16(af[i], bfr[j], acc[i][j], 0, 0, 0);
    }

    const int cn = lane & 15;
    const int cm = (lane >> 4) * 4;
    float bv[4];
#pragma unroll
    for (int j = 0; j < 4; ++j)
        bv[j] = bias[n0 + wn * 64 + j * 16 + cn];
#pragma unroll
    for (int i = 0; i < 4; ++i) {
        const int m = m0 + wm * 64 + i * 16 + cm;
#pragma unroll
        for (int j = 0; j < 4; ++j) {
            const int n = n0 + wn * 64 + j * 16 + cn;
            const size_t base = (size_t)m * Ndim + n;
#pragma unroll
            for (int r = 0; r < 4; ++r)
                C[base + (size_t)r * Ndim] = acc[i][j][r] + bv[j];
        }
    }
}

__global__ __launch_bounds__(256) void lora_rmw(
    const float* __restrict__ x,
    const float* __restrict__ Waq, const float* __restrict__ Wbq,
    const float* __restrict__ Wav, const float* __restrict__ Wbv,
    float* __restrict__ out)
{
    __shared__ float Pq[64][16];
    __shared__ float Pv[64][16];
    const int t  = threadIdx.x;
    const int m0 = blockIdx.x * 64;
    {
        const int row = t >> 2;
        const int r0  = (t & 3) * 4;
        float accq[4] = {0.f, 0.f, 0.f, 0.f};
        float accv[4] = {0.f, 0.f, 0.f, 0.f};
        const float* xr = x + (size_t)(m0 + row) * Kdim;
        for (int d = 0; d < Kdim; d += 4) {
            floatx4 xv = *(const floatx4*)(xr + d);
#pragma unroll
            for (int rr = 0; rr < 4; ++rr) {
                floatx4 wq = *(const floatx4*)(Waq + (size_t)(r0 + rr) * Kdim + d);
                floatx4 wv = *(const floatx4*)(Wav + (size_t)(r0 + rr) * Kdim + d);
#pragma unroll
                for (int e = 0; e < 4; ++e) {
                    accq[rr] += xv[e] * wq[e];
                    accv[rr] += xv[e] * wv[e];
                }
            }
        }
#pragma unroll
        for (int rr = 0; rr < 4; ++rr) {
            Pq[row][r0 + rr] = accq[rr];
            Pv[row][r0 + rr] = accv[rr];
        }
    }
    __syncthreads();
    const int col  = t * 8;
    const bool isq = col < 1024;
    const int nn0  = isq ? col : col - 1024;
    const int n    = isq ? col : col + 1024;
    const float* Wb = isq ? Wbq : Wbv;
    for (int row = 0; row < 64; ++row) {
        const float* P = isq ? Pq[row] : Pv[row];
        const size_t off = (size_t)(m0 + row) * Ndim + n;
        floatx4 o0 = *(const floatx4*)(out + off);
        floatx4 o1 = *(const floatx4*)(out + off + 4);
#pragma unroll
        for (int i = 0; i < 8; ++i) {
            floatx4 w0 = *(const floatx4*)(Wb + (size_t)(nn0 + i) * 16);
            floatx4 w1 = *(const floatx4*)(Wb + (size_t)(nn0 + i) * 16 + 4);
            floatx4 w2 = *(const floatx4*)(Wb + (size_t)(nn0 + i) * 16 + 8);
            floatx4 w3 = *(const floatx4*)(Wb + (size_t)(nn0 + i) * 16 + 12);
            float s = 0.f;
#pragma unroll
            for (int r = 0; r < 4; ++r)
                s += P[r] * w0[r] + P[r + 4] * w1[r] + P[r + 8] * w2[r] + P[r + 12] * w3[r];
            if (i < 4) o0[i] += s; else o1[i - 4] += s;
        }
        *(floatx4*)(out + off)     = o0;
        *(floatx4*)(out + off + 4) = o1;
    }
}

extern "C" void kernel_launch(void* const* d_in, const int* in_sizes, int n_in,
                              void* d_out, int out_size, void* d_ws, size_t ws_size,
                              hipStream_t stream)
{
    (void)in_sizes; (void)n_in; (void)out_size;
    const float* x    = (const float*)d_in[0];
    const float* Wqkv = (const float*)d_in[1];
    const float* bqkv = (const float*)d_in[2];
    const float* Waq  = (const float*)d_in[3];
    const float* Wbq  = (const float*)d_in[4];
    const float* Wav  = (const float*)d_in[5];
    const float* Wbv  = (const float*)d_in[6];
    float* out = (float*)d_out;

    const size_t WEFF_BYTES = (size_t)Ndim * Kdim * sizeof(__hip_bfloat16); // 6.3 MB
    const size_t XB_BYTES   = (size_t)Mdim * Kdim * sizeof(__hip_bfloat16); // 33.5 MB

    if (ws_size >= WEFF_BYTES + XB_BYTES) {
        // fast path: fold LoRA into bf16 W_eff, bf16 x, single MFMA GEMM
        __hip_bfloat16* Weff = (__hip_bfloat16*)d_ws;
        __hip_bfloat16* xb   = (__hip_bfloat16*)((char*)d_ws + WEFF_BYTES);
        build_weff<<<(Ndim * Kdim / 4) / 256, 256, 0, stream>>>(Wqkv, Waq, Wbq, Wav, Wbv, Weff);
        cvt_x<<<(int)(((size_t)Mdim * Kdim / 8) / 256), 256, 0, stream>>>(x, xb);
        gemm_bf16_v4<<<512, 256, 0, stream>>>(xb, Weff, bqkv, out);
    } else {
        // fallback: R2 proven path (no scratch)
        gemm_bias_f32<<<(Mdim / 128) * (Ndim / 128), 256, 0, stream>>>(x, Wqkv, bqkv, out);
        lora_rmw<<<Mdim / 64, 256, 0, stream>>>(x, Waq, Wbq, Wav, Wbv, out);
    }
}

// Round 4
// 378.515 us; speedup vs baseline: 1.1493x; 1.1493x over previous
//
#include <hip/hip_runtime.h>
#include <hip/hip_bf16.h>

typedef __bf16 bf16x4 __attribute__((ext_vector_type(4)));
typedef __bf16 bf16x8 __attribute__((ext_vector_type(8)));
typedef float floatx4 __attribute__((ext_vector_type(4)));

#define GLD16(gp, lp) __builtin_amdgcn_global_load_lds(                      \
    (const __attribute__((address_space(1))) void*)(gp),                     \
    (__attribute__((address_space(3))) void*)(lp), 16, 0, 0)

constexpr int Mdim = 16384;   // B*S
constexpr int Ndim = 3072;    // 3*D
constexpr int Kdim = 1024;    // D

static __device__ __forceinline__ bf16x8 cvt8(floatx4 lo, floatx4 hi) {
    bf16x8 r;
#pragma unroll
    for (int e = 0; e < 4; ++e) { r[e] = (__bf16)lo[e]; r[e + 4] = (__bf16)hi[e]; }
    return r;
}

// ===========================================================================
// FAST PATH (requires ws_size >= 40 MB)
// ===========================================================================

// --- prep 1: W_eff = W_qkv + LoRA fold, fp32 accumulate -> bf16 ------------
__global__ __launch_bounds__(256) void build_weff(
    const float* __restrict__ Wqkv,   // 3072 x 1024
    const float* __restrict__ Waq,    // 16 x 1024
    const float* __restrict__ Wbq,    // 1024 x 16
    const float* __restrict__ Wav,    // 16 x 1024
    const float* __restrict__ Wbv,    // 1024 x 16
    __hip_bfloat16* __restrict__ Weff)
{
    const int idx = (blockIdx.x * 256 + threadIdx.x) * 4;  // e*1024 + d
    const int e = idx >> 10;
    const int d = idx & 1023;
    floatx4 v = *(const floatx4*)(Wqkv + idx);
    if (e < 1024) {
#pragma unroll
        for (int r = 0; r < 16; ++r) {
            const float wb = Wbq[e * 16 + r];
            floatx4 wa = *(const floatx4*)(Waq + r * 1024 + d);
#pragma unroll
            for (int q = 0; q < 4; ++q) v[q] += wb * wa[q];
        }
    } else if (e >= 2048) {
        const int e2 = e - 2048;
#pragma unroll
        for (int r = 0; r < 16; ++r) {
            const float wb = Wbv[e2 * 16 + r];
            floatx4 wa = *(const floatx4*)(Wav + r * 1024 + d);
#pragma unroll
            for (int q = 0; q < 4; ++q) v[q] += wb * wa[q];
        }
    }
    bf16x4 o;
#pragma unroll
    for (int q = 0; q < 4; ++q) o[q] = (__bf16)v[q];
    *(bf16x4*)(Weff + idx) = o;
}

// --- prep 2: x fp32 -> bf16 -------------------------------------------------
__global__ __launch_bounds__(256) void cvt_x(
    const float* __restrict__ x, __hip_bfloat16* __restrict__ xb)
{
    const size_t idx = ((size_t)blockIdx.x * 256 + threadIdx.x) * 8;
    bf16x8 r = cvt8(*(const floatx4*)(x + idx), *(const floatx4*)(x + idx + 4));
    *(bf16x8*)(xb + idx) = r;
}

// --- main GEMM v5: v3 K-loop (verified) + LDS-staged coalesced epilogue ----
// v3 base: 128x128 tile, BK=64, dbuf LDS, 2 blocks/CU, both-sides XOR
// swizzle (0 bank conflicts), counted vmcnt(8), setprio, XCD swizzle.
// NEW: epilogue stages C-tile through LDS (fp32 [128][132], pad -> 2-way-free
// scatter) and stores full 128-B lines (32 lanes x 16 B contiguous/row).
// This removes the L2 write-allocate RMW fetch of the old 64-B half-line
// stores (~200 MB of HBM re-fetch in v3's FETCH_SIZE).
__global__ __launch_bounds__(256, 2) void gemm_bf16_v5(
    const __hip_bfloat16* __restrict__ A,     // M x K bf16
    const __hip_bfloat16* __restrict__ Bw,    // N x K bf16 (W_eff)
    const float* __restrict__ bias,           // N fp32
    float* __restrict__ C)                    // M x N fp32
{
    constexpr int NT = Kdim / 64;             // 16 K-tiles
    // union: K-loop uses 2 dbuf x (A,B) x 16 KiB = 64 KiB bf16 tiles;
    // epilogue reuses as fp32 [128][132] = 67.6 KiB. 2 blocks/CU (135<160).
    __shared__ __align__(16) char smem[128 * 132 * 4];

    const int t    = threadIdx.x;
    const int wave = t >> 6;
    const int lane = t & 63;
    const int wm   = wave >> 1;       // 2x2 wave grid, 64x64 output each
    const int wn   = wave & 1;

    // XCD-aware block swizzle (3072 blocks, 3072 % 8 == 0 -> bijective)
    constexpr int NWG = (Mdim / 128) * (Ndim / 128);  // 3072
    const int bid = (blockIdx.x & 7) * (NWG >> 3) + (blockIdx.x >> 3);
    const int bx  = bid % (Ndim / 128);   // n fastest: neighbors share A-panel
    const int by  = bid / (Ndim / 128);
    const int m0  = by * 128;
    const int n0  = bx * 128;

    // --- staging geometry: LDS dest LINEAR; bank swizzle applied by
    // permuting the GLOBAL source column (rule #21). 4 GLD16/thread/matrix.
    const int srow0 = t >> 3;                              // 0..31
    const int scb_s = ((t & 7) * 16) ^ ((srow0 & 7) << 4); // swizzled src col-byte

#define STAGE_TILE(nb_, kt_) do {                                              \
    const __hip_bfloat16* _ga = A  + (size_t)(m0 + srow0) * Kdim               \
                                + (kt_) * 64 + (scb_s >> 1);                   \
    const __hip_bfloat16* _gb = Bw + (size_t)(n0 + srow0) * Kdim               \
                                + (kt_) * 64 + (scb_s >> 1);                   \
    char* _la = smem + (nb_) * 32768 + t * 16;                                 \
    char* _lb = _la + 16384;                                                   \
    GLD16(_ga,                      _la);                                      \
    GLD16(_ga + (size_t)32 * Kdim,  _la + 4096);                               \
    GLD16(_ga + (size_t)64 * Kdim,  _la + 8192);                               \
    GLD16(_ga + (size_t)96 * Kdim,  _la + 12288);                              \
    GLD16(_gb,                      _lb);                                      \
    GLD16(_gb + (size_t)32 * Kdim,  _lb + 4096);                               \
    GLD16(_gb + (size_t)64 * Kdim,  _lb + 8192);                               \
    GLD16(_gb + (size_t)96 * Kdim,  _lb + 12288);                              \
} while (0)

    // --- frag-read geometry (v3-verified, bank-conflict-free)
    const int fm   = lane & 15;
    const int fk2  = (lane >> 4) * 16;
    const int fxor = (fm & 7) << 4;
    const int cbs0 = fk2 ^ fxor;              // k 0..31
    const int cbs1 = (64 + fk2) ^ fxor;       // k 32..63

    floatx4 acc[4][4];
#pragma unroll
    for (int i = 0; i < 4; ++i)
#pragma unroll
        for (int j = 0; j < 4; ++j)
            acc[i][j] = (floatx4){0.f, 0.f, 0.f, 0.f};

    // prologue: stage tile 0 into buf 0
    STAGE_TILE(0, 0);

    for (int kt = 0; kt < NT; ++kt) {
        const int nb = kt & 1;
        if (kt + 1 < NT) {
            STAGE_TILE(nb ^ 1, kt + 1);
            asm volatile("s_waitcnt vmcnt(8)" ::: "memory");
        } else {
            asm volatile("s_waitcnt vmcnt(0)" ::: "memory");
        }
        __builtin_amdgcn_s_barrier();          // all waves' stages visible

        const char* Ab = smem + nb * 32768;
        const char* Bb = Ab + 16384;
        bf16x8 aq[2][4], bq[2][4];
#pragma unroll
        for (int i = 0; i < 4; ++i) {
            aq[0][i] = *(const bf16x8*)(Ab + (wm * 64 + i * 16 + fm) * 128 + cbs0);
            aq[1][i] = *(const bf16x8*)(Ab + (wm * 64 + i * 16 + fm) * 128 + cbs1);
            bq[0][i] = *(const bf16x8*)(Bb + (wn * 64 + i * 16 + fm) * 128 + cbs0);
            bq[1][i] = *(const bf16x8*)(Bb + (wn * 64 + i * 16 + fm) * 128 + cbs1);
        }
        __builtin_amdgcn_s_setprio(1);
#pragma unroll
        for (int kk = 0; kk < 2; ++kk)
#pragma unroll
            for (int i = 0; i < 4; ++i)
#pragma unroll
                for (int j = 0; j < 4; ++j)
                    acc[i][j] = __builtin_amdgcn_mfma_f32_16x16x32_bf16(
                        aq[kk][i], bq[kk][j], acc[i][j], 0, 0, 0);
        __builtin_amdgcn_s_setprio(0);
        if (kt + 1 < NT)
            __builtin_amdgcn_s_barrier();      // reads done before next stage
    }

    // ---- epilogue: acc(+bias) -> LDS fp32 [128][132] -> full-line stores ---
    const int cn = lane & 15;
    const int cm = (lane >> 4) * 4;
    float bv[4];
#pragma unroll
    for (int j = 0; j < 4; ++j)
        bv[j] = bias[n0 + wn * 64 + j * 16 + cn];

    __syncthreads();                  // everyone done reading K-loop tiles
    float* ep = (float*)smem;         // [128][132] fp32, +4 pad: scatter 2-way-free
#pragma unroll
    for (int i = 0; i < 4; ++i) {
        const int rl = wm * 64 + i * 16 + cm;          // local row (+reg r)
#pragma unroll
        for (int j = 0; j < 4; ++j) {
            const int cl = wn * 64 + j * 16 + cn;      // local col
#pragma unroll
            for (int r = 0; r < 4; ++r)
                ep[(rl + r) * 132 + cl] = acc[i][j][r] + bv[j];
        }
    }
    __syncthreads();
    // read back row-major; one store = 32 lanes x 16 B = 512 B contiguous
    const int rrow = wave * 2 + (lane >> 5);           // 0..7
    const int rcol = (lane & 31) * 4;                  // 0..124
#pragma unroll
    for (int it = 0; it < 16; ++it) {
        const int row = it * 8 + rrow;
        floatx4 v = *(const floatx4*)&ep[row * 132 + rcol];
        *(floatx4*)&C[(size_t)(m0 + row) * Ndim + n0 + rcol] = v;
    }
#undef STAGE_TILE
}

// ===========================================================================
// FALLBACK PATH (R2, proven): used only if ws_size < 40 MB
// ===========================================================================

__global__ __launch_bounds__(256, 2) void gemm_bias_f32(
    const float* __restrict__ A, const float* __restrict__ Bw,
    const float* __restrict__ bias, float* __restrict__ C)
{
    constexpr int TK = 32;
    __shared__ __hip_bfloat16 As[128 * TK];
    __shared__ __hip_bfloat16 Bs[128 * TK];

    const int t    = threadIdx.x;
    const int wave = t >> 6;
    const int lane = t & 63;
    const int bx   = blockIdx.x % (Ndim / 128);
    const int by   = blockIdx.x / (Ndim / 128);
    const int m0   = by * 128;
    const int n0   = bx * 128;
    const int wm   = wave >> 1;
    const int wn   = wave & 1;
    const int srow = wave * 16 + (lane >> 2);
    const int scol = (lane & 3) * 8;

    const float* Ag0 = A  + (size_t)(m0 + srow) * Kdim + scol;
    const float* Ag1 = Ag0 + (size_t)64 * Kdim;
    const float* Bg0 = Bw + (size_t)(n0 + srow) * Kdim + scol;
    const float* Bg1 = Bg0 + (size_t)64 * Kdim;

    __hip_bfloat16* Al0 = &As[srow * TK + scol];
    __hip_bfloat16* Al1 = &As[(srow + 64) * TK + scol];
    __hip_bfloat16* Bl0 = &Bs[srow * TK + scol];
    __hip_bfloat16* Bl1 = &Bs[(srow + 64) * TK + scol];

    const int fm = lane & 15;
    const int fk = (lane >> 4) * 8;

    floatx4 acc[4][4];
#pragma unroll
    for (int i = 0; i < 4; ++i)
#pragma unroll
        for (int j = 0; j < 4; ++j)
            acc[i][j] = (floatx4){0.f, 0.f, 0.f, 0.f};

    for (int kt = 0; kt < Kdim; kt += TK) {
        bf16x8 a0 = cvt8(*(const floatx4*)(Ag0 + kt), *(const floatx4*)(Ag0 + kt + 4));
        bf16x8 a1 = cvt8(*(const floatx4*)(Ag1 + kt), *(const floatx4*)(Ag1 + kt + 4));
        bf16x8 b0 = cvt8(*(const floatx4*)(Bg0 + kt), *(const floatx4*)(Bg0 + kt + 4));
        bf16x8 b1 = cvt8(*(const floatx4*)(Bg1 + kt), *(const floatx4*)(Bg1 + kt + 4));
        __syncthreads();
        *(bf16x8*)Al0 = a0;
        *(bf16x8*)Al1 = a1;
        *(bf16x8*)Bl0 = b0;
        *(bf16x8*)Bl1 = b1;
        __syncthreads();

        bf16x8 af[4], bfr[4];
#pragma unroll
        for (int i = 0; i < 4; ++i) {
            af[i]  = *(const bf16x8*)&As[(wm * 64 + i * 16 + fm) * TK + fk];
            bfr[i] = *(const bf16x8*)&Bs[(wn * 64 + i * 16 + fm) * TK + fk];
        }
#pragma unroll
        for (int i = 0; i < 4; ++i)
#pragma unroll
            for (int j = 0; j < 4; ++j)
                acc[i][j] = __builtin_amdgcn_mfma_f32_16x16x32_bf16(af[i], bfr[j], acc[i][j], 0, 0, 0);
    }

    const int cn = lane & 15;
    const int cm = (lane >> 4) * 4;
    float bv[4];
#pragma unroll
    for (int j = 0; j < 4; ++j)
        bv[j] = bias[n0 + wn * 64 + j * 16 + cn];
#pragma unroll
    for (int i = 0; i < 4; ++i) {
        const int m = m0 + wm * 64 + i * 16 + cm;
#pragma unroll
        for (int j = 0; j < 4; ++j) {
            const int n = n0 + wn * 64 + j * 16 + cn;
            const size_t base = (size_t)m * Ndim + n;
#pragma unroll
            for (int r = 0; r < 4; ++r)
                C[base + (size_t)r * Ndim] = acc[i][j][r] + bv[j];
        }
    }
}

__global__ __launch_bounds__(256) void lora_rmw(
    const float* __restrict__ x,
    const float* __restrict__ Waq, const float* __restrict__ Wbq,
    const float* __restrict__ Wav, const float* __restrict__ Wbv,
    float* __restrict__ out)
{
    __shared__ float Pq[64][16];
    __shared__ float Pv[64][16];
    const int t  = threadIdx.x;
    const int m0 = blockIdx.x * 64;
    {
        const int row = t >> 2;
        const int r0  = (t & 3) * 4;
        float accq[4] = {0.f, 0.f, 0.f, 0.f};
        float accv[4] = {0.f, 0.f, 0.f, 0.f};
        const float* xr = x + (size_t)(m0 + row) * Kdim;
        for (int d = 0; d < Kdim; d += 4) {
            floatx4 xv = *(const floatx4*)(xr + d);
#pragma unroll
            for (int rr = 0; rr < 4; ++rr) {
                floatx4 wq = *(const floatx4*)(Waq + (size_t)(r0 + rr) * Kdim + d);
                floatx4 wv = *(const floatx4*)(Wav + (size_t)(r0 + rr) * Kdim + d);
#pragma unroll
                for (int e = 0; e < 4; ++e) {
                    accq[rr] += xv[e] * wq[e];
                    accv[rr] += xv[e] * wv[e];
                }
            }
        }
#pragma unroll
        for (int rr = 0; rr < 4; ++rr) {
            Pq[row][r0 + rr] = accq[rr];
            Pv[row][r0 + rr] = accv[rr];
        }
    }
    __syncthreads();
    const int col  = t * 8;
    const bool isq = col < 1024;
    const int nn0  = isq ? col : col - 1024;
    const int n    = isq ? col : col + 1024;
    const float* Wb = isq ? Wbq : Wbv;
    for (int row = 0; row < 64; ++row) {
        const float* P = isq ? Pq[row] : Pv[row];
        const size_t off = (size_t)(m0 + row) * Ndim + n;
        floatx4 o0 = *(const floatx4*)(out + off);
        floatx4 o1 = *(const floatx4*)(out + off + 4);
#pragma unroll
        for (int i = 0; i < 8; ++i) {
            floatx4 w0 = *(const floatx4*)(Wb + (size_t)(nn0 + i) * 16);
            floatx4 w1 = *(const floatx4*)(Wb + (size_t)(nn0 + i) * 16 + 4);
            floatx4 w2 = *(const floatx4*)(Wb + (size_t)(nn0 + i) * 16 + 8);
            floatx4 w3 = *(const floatx4*)(Wb + (size_t)(nn0 + i) * 16 + 12);
            float s = 0.f;
#pragma unroll
            for (int r = 0; r < 4; ++r)
                s += P[r] * w0[r] + P[r + 4] * w1[r] + P[r + 8] * w2[r] + P[r + 12] * w3[r];
            if (i < 4) o0[i] += s; else o1[i - 4] += s;
        }
        *(floatx4*)(out + off)     = o0;
        *(floatx4*)(out + off + 4) = o1;
    }
}

extern "C" void kernel_launch(void* const* d_in, const int* in_sizes, int n_in,
                              void* d_out, int out_size, void* d_ws, size_t ws_size,
                              hipStream_t stream)
{
    (void)in_sizes; (void)n_in; (void)out_size;
    const float* x    = (const float*)d_in[0];
    const float* Wqkv = (const float*)d_in[1];
    const float* bqkv = (const float*)d_in[2];
    const float* Waq  = (const float*)d_in[3];
    const float* Wbq  = (const float*)d_in[4];
    const float* Wav  = (const float*)d_in[5];
    const float* Wbv  = (const float*)d_in[6];
    float* out = (float*)d_out;

    const size_t WEFF_BYTES = (size_t)Ndim * Kdim * sizeof(__hip_bfloat16); // 6.3 MB
    const size_t XB_BYTES   = (size_t)Mdim * Kdim * sizeof(__hip_bfloat16); // 33.5 MB

    if (ws_size >= WEFF_BYTES + XB_BYTES) {
        // fast path: fold LoRA into bf16 W_eff, bf16 x, single MFMA GEMM
        __hip_bfloat16* Weff = (__hip_bfloat16*)d_ws;
        __hip_bfloat16* xb   = (__hip_bfloat16*)((char*)d_ws + WEFF_BYTES);
        build_weff<<<(Ndim * Kdim / 4) / 256, 256, 0, stream>>>(Wqkv, Waq, Wbq, Wav, Wbv, Weff);
        cvt_x<<<(int)(((size_t)Mdim * Kdim / 8) / 256), 256, 0, stream>>>(x, xb);
        gemm_bf16_v5<<<(Mdim / 128) * (Ndim / 128), 256, 0, stream>>>(xb, Weff, bqkv, out);
    } else {
        // fallback: R2 proven path (no scratch)
        gemm_bias_f32<<<(Mdim / 128) * (Ndim / 128), 256, 0, stream>>>(x, Wqkv, bqkv, out);
        lora_rmw<<<Mdim / 64, 256, 0, stream>>>(x, Waq, Wbq, Wav, Wbv, out);
    }
}

// Round 5
// 360.298 us; speedup vs baseline: 1.2074x; 1.0506x over previous
//
#include <hip/hip_runtime.h>
#include <hip/hip_bf16.h>

typedef __bf16 bf16x4 __attribute__((ext_vector_type(4)));
typedef __bf16 bf16x8 __attribute__((ext_vector_type(8)));
typedef float floatx4 __attribute__((ext_vector_type(4)));

#define GLD16(gp, lp) __builtin_amdgcn_global_load_lds(                      \
    (const __attribute__((address_space(1))) void*)(gp),                     \
    (__attribute__((address_space(3))) void*)(lp), 16, 0, 0)

constexpr int Mdim = 16384;   // B*S
constexpr int Ndim = 3072;    // 3*D
constexpr int Kdim = 1024;    // D

static __device__ __forceinline__ bf16x8 cvt8(floatx4 lo, floatx4 hi) {
    bf16x8 r;
#pragma unroll
    for (int e = 0; e < 4; ++e) { r[e] = (__bf16)lo[e]; r[e + 4] = (__bf16)hi[e]; }
    return r;
}

// ===========================================================================
// FAST PATH (requires ws_size >= 40 MB)
// ===========================================================================

// --- prep 1: W_eff = W_qkv + LoRA fold, fp32 accumulate -> bf16 ------------
__global__ __launch_bounds__(256) void build_weff(
    const float* __restrict__ Wqkv,   // 3072 x 1024
    const float* __restrict__ Waq,    // 16 x 1024
    const float* __restrict__ Wbq,    // 1024 x 16
    const float* __restrict__ Wav,    // 16 x 1024
    const float* __restrict__ Wbv,    // 1024 x 16
    __hip_bfloat16* __restrict__ Weff)
{
    const int idx = (blockIdx.x * 256 + threadIdx.x) * 4;  // e*1024 + d
    const int e = idx >> 10;
    const int d = idx & 1023;
    floatx4 v = *(const floatx4*)(Wqkv + idx);
    if (e < 1024) {
#pragma unroll
        for (int r = 0; r < 16; ++r) {
            const float wb = Wbq[e * 16 + r];
            floatx4 wa = *(const floatx4*)(Waq + r * 1024 + d);
#pragma unroll
            for (int q = 0; q < 4; ++q) v[q] += wb * wa[q];
        }
    } else if (e >= 2048) {
        const int e2 = e - 2048;
#pragma unroll
        for (int r = 0; r < 16; ++r) {
            const float wb = Wbv[e2 * 16 + r];
            floatx4 wa = *(const floatx4*)(Wav + r * 1024 + d);
#pragma unroll
            for (int q = 0; q < 4; ++q) v[q] += wb * wa[q];
        }
    }
    bf16x4 o;
#pragma unroll
    for (int q = 0; q < 4; ++q) o[q] = (__bf16)v[q];
    *(bf16x4*)(Weff + idx) = o;
}

// --- prep 2: x fp32 -> bf16 -------------------------------------------------
__global__ __launch_bounds__(256) void cvt_x(
    const float* __restrict__ x, __hip_bfloat16* __restrict__ xb)
{
    const size_t idx = ((size_t)blockIdx.x * 256 + threadIdx.x) * 8;
    bf16x8 r = cvt8(*(const floatx4*)(x + idx), *(const floatx4*)(x + idx + 4));
    *(bf16x8*)(xb + idx) = r;
}

// --- main GEMM v6: 256x256 tile, BK=64, 8 waves, m201-style phase schedule -
// Per K-tile t: 4 phases (one output quadrant each, 16 MFMA), stage one
// half-tile per phase with 3-half-tile prefetch depth, vmcnt(6) ONCE per
// K-tile, only 3 barriers per K-tile. Hazard-derived staging order:
//   p0: A-h1(t+1) [other buf]   p1: B-h1(t+1) [other buf]
//   p2: B-h0(t+2) [same buf, safe after barrier b]
//   p3: A-h0(t+2) [same buf, safe after barrier c]
// Both-sides XOR bank swizzle (verified 0 conflicts), setprio on MFMA,
// bijective XCD swizzle (768 % 8 == 0).
__global__ __launch_bounds__(512, 2) void gemm_bf16_v6(
    const __hip_bfloat16* __restrict__ A,     // M x K bf16
    const __hip_bfloat16* __restrict__ Bw,    // N x K bf16 (W_eff)
    const float* __restrict__ bias,           // N fp32
    float* __restrict__ C)                    // M x N fp32
{
    constexpr int NT = Kdim / 64;             // 16 K-tiles
    // buf b at b*65536; A half h at +h*16384; B at +32768+h*16384. 128 KiB.
    __shared__ __align__(16) char smem[131072];

    const int t    = threadIdx.x;
    const int wid  = t >> 6;
    const int lane = t & 63;
    const int wm   = wid >> 2;        // 2 wave-rows, 128 out-rows each
    const int wn   = wid & 3;         // 4 wave-cols, 64 out-cols each

    constexpr int NWG = (Mdim / 256) * (Ndim / 256);  // 768, %8==0 -> bijective
    const int bid = (blockIdx.x & 7) * (NWG >> 3) + (blockIdx.x >> 3);
    const int bx  = bid % (Ndim / 256);
    const int by  = bid / (Ndim / 256);
    const int m0  = by * 256;
    const int n0  = bx * 256;

    // staging: linear LDS dest (t*16), swizzle via pre-permuted global col.
    const int srow0 = t >> 3;                              // 0..63
    const int scb   = ((t & 7) * 16) ^ ((srow0 & 7) << 4); // swizzled col-byte
    const __hip_bfloat16* Ag = A  + (size_t)(m0 + srow0) * Kdim + (scb >> 1);
    const __hip_bfloat16* Bg = Bw + (size_t)(n0 + srow0) * Kdim + (scb >> 1);

    // stage half h of matrix mat (0=A,1=B) for K-tile kt_ into buffer b_
#define STG(mat, h, kt_, b_) do {                                              \
    const __hip_bfloat16* _g = ((mat) ? Bg : Ag)                               \
        + (size_t)((h) * 128) * Kdim + (kt_) * 64;                             \
    char* _l = smem + (b_) * 65536 + (mat) * 32768 + (h) * 16384 + t * 16;     \
    GLD16(_g,                     _l);                                         \
    GLD16(_g + (size_t)64 * Kdim, _l + 8192);                                  \
} while (0)

    // frag-read geometry: row stride 128 B; frag rows ≡ fm (mod 8) always.
    const int fm  = lane & 15;
    const int fk2 = (lane >> 4) * 16;
    const int fx  = (fm & 7) << 4;
    const int cb0 = fk2 ^ fx;             // k 0..31
    const int cb1 = (64 + fk2) ^ fx;      // k 32..63

    floatx4 acc[8][4];
#pragma unroll
    for (int i = 0; i < 8; ++i)
#pragma unroll
        for (int j = 0; j < 4; ++j)
            acc[i][j] = (floatx4){0.f, 0.f, 0.f, 0.f};

#define MFMA_Q(mq, nq, BQ)                                                     \
    __builtin_amdgcn_s_setprio(1);                                             \
    _Pragma("unroll")                                                          \
    for (int i = 0; i < 4; ++i)                                                \
        _Pragma("unroll")                                                      \
        for (int j = 0; j < 2; ++j) {                                          \
            acc[(mq) * 4 + i][(nq) * 2 + j] =                                  \
                __builtin_amdgcn_mfma_f32_16x16x32_bf16(                       \
                    aq[i][0], BQ[j][0], acc[(mq) * 4 + i][(nq) * 2 + j], 0,0,0);\
            acc[(mq) * 4 + i][(nq) * 2 + j] =                                  \
                __builtin_amdgcn_mfma_f32_16x16x32_bf16(                       \
                    aq[i][1], BQ[j][1], acc[(mq) * 4 + i][(nq) * 2 + j], 0,0,0);\
        }                                                                      \
    __builtin_amdgcn_s_setprio(0);

    // prologue: queue = A0(0) A1(0) B0(0) B1(0) B0(1) A0(1)  [12 ops]
    STG(0, 0, 0, 0); STG(0, 1, 0, 0); STG(1, 0, 0, 0); STG(1, 1, 0, 0);
    STG(1, 0, 1, 1); STG(0, 0, 1, 1);

    bf16x8 aq[4][2], bq0[2][2], bq1[2][2];

    for (int kt = 0; kt < NT; ++kt) {
        const int b = kt & 1;
        const char* Ab = smem + b * 65536;
        const char* Bb = Ab + 32768;

        // ---- P0: quad(0,0) ----
        if (kt + 1 < NT) {
            STG(0, 1, kt + 1, b ^ 1);            // A-h1(t+1)
            asm volatile("s_waitcnt vmcnt(6)" ::: "memory");  // tile t landed
        } else {
            asm volatile("s_waitcnt vmcnt(0)" ::: "memory");
        }
        __builtin_amdgcn_s_barrier();            // (a): tile-t buffer visible
        __builtin_amdgcn_sched_barrier(0x8);     // pin loads; MFMA may cross
#pragma unroll
        for (int i = 0; i < 4; ++i) {
            const char* ar = Ab + (wm * 128 + i * 16 + fm) * 128;
            aq[i][0] = *(const bf16x8*)(ar + cb0);
            aq[i][1] = *(const bf16x8*)(ar + cb1);
        }
#pragma unroll
        for (int j = 0; j < 2; ++j) {
            const char* br = Bb + (wn * 64 + j * 16 + fm) * 128;
            bq0[j][0] = *(const bf16x8*)(br + cb0);
            bq0[j][1] = *(const bf16x8*)(br + cb1);
        }
        MFMA_Q(0, 0, bq0)

        // ---- P1: quad(0,1) ----
#pragma unroll
        for (int j = 0; j < 2; ++j) {
            const char* br = Bb + (wn * 64 + 32 + j * 16 + fm) * 128;
            bq1[j][0] = *(const bf16x8*)(br + cb0);
            bq1[j][1] = *(const bf16x8*)(br + cb1);
        }
        if (kt + 1 < NT) STG(1, 1, kt + 1, b ^ 1);   // B-h1(t+1), other buf
        MFMA_Q(0, 1, bq1)
        __builtin_amdgcn_s_barrier();            // (b): all B(t)/aq0 reads done
        __builtin_amdgcn_sched_barrier(0x108);   // ds_read+MFMA may cross, VMEM pinned

        // ---- P2: quad(1,0) ----
#pragma unroll
        for (int i = 0; i < 4; ++i) {
            const char* ar = Ab + (wm * 128 + 64 + i * 16 + fm) * 128;
            aq[i][0] = *(const bf16x8*)(ar + cb0);
            aq[i][1] = *(const bf16x8*)(ar + cb1);
        }
        if (kt + 2 < NT) STG(1, 0, kt + 2, b);       // B-h0(t+2), same buf (safe: b)
        MFMA_Q(1, 0, bq0)
        __builtin_amdgcn_s_barrier();            // (c): all aq1 reads done
        __builtin_amdgcn_sched_barrier(0x108);

        // ---- P3: quad(1,1) ---- (register-only MFMA; overlaps next P0)
        if (kt + 2 < NT) STG(0, 0, kt + 2, b);       // A-h0(t+2), same buf (safe: c)
        MFMA_Q(1, 1, bq1)
    }

    // epilogue: C/D layout col(n)=lane&15, row(m)=(lane>>4)*4 + reg
    const int cn = lane & 15;
    const int cm = (lane >> 4) * 4;
    float bv[4];
#pragma unroll
    for (int j = 0; j < 4; ++j)
        bv[j] = bias[n0 + wn * 64 + j * 16 + cn];

#pragma unroll
    for (int mi = 0; mi < 8; ++mi) {
        const int m = m0 + wm * 128 + mi * 16 + cm;
#pragma unroll
        for (int ni = 0; ni < 4; ++ni) {
            const int n = n0 + wn * 64 + ni * 16 + cn;
            const size_t base = (size_t)m * Ndim + n;
#pragma unroll
            for (int r = 0; r < 4; ++r)
                C[base + (size_t)r * Ndim] = acc[mi][ni][r] + bv[ni];
        }
    }
#undef STG
#undef MFMA_Q
}

// ===========================================================================
// FALLBACK PATH (R2, proven): used only if ws_size < 40 MB
// ===========================================================================

__global__ __launch_bounds__(256, 2) void gemm_bias_f32(
    const float* __restrict__ A, const float* __restrict__ Bw,
    const float* __restrict__ bias, float* __restrict__ C)
{
    constexpr int TK = 32;
    __shared__ __hip_bfloat16 As[128 * TK];
    __shared__ __hip_bfloat16 Bs[128 * TK];

    const int t    = threadIdx.x;
    const int wave = t >> 6;
    const int lane = t & 63;
    const int bx   = blockIdx.x % (Ndim / 128);
    const int by   = blockIdx.x / (Ndim / 128);
    const int m0   = by * 128;
    const int n0   = bx * 128;
    const int wm   = wave >> 1;
    const int wn   = wave & 1;
    const int srow = wave * 16 + (lane >> 2);
    const int scol = (lane & 3) * 8;

    const float* Ag0 = A  + (size_t)(m0 + srow) * Kdim + scol;
    const float* Ag1 = Ag0 + (size_t)64 * Kdim;
    const float* Bg0 = Bw + (size_t)(n0 + srow) * Kdim + scol;
    const float* Bg1 = Bg0 + (size_t)64 * Kdim;

    __hip_bfloat16* Al0 = &As[srow * TK + scol];
    __hip_bfloat16* Al1 = &As[(srow + 64) * TK + scol];
    __hip_bfloat16* Bl0 = &Bs[srow * TK + scol];
    __hip_bfloat16* Bl1 = &Bs[(srow + 64) * TK + scol];

    const int fm = lane & 15;
    const int fk = (lane >> 4) * 8;

    floatx4 acc[4][4];
#pragma unroll
    for (int i = 0; i < 4; ++i)
#pragma unroll
        for (int j = 0; j < 4; ++j)
            acc[i][j] = (floatx4){0.f, 0.f, 0.f, 0.f};

    for (int kt = 0; kt < Kdim; kt += TK) {
        bf16x8 a0 = cvt8(*(const floatx4*)(Ag0 + kt), *(const floatx4*)(Ag0 + kt + 4));
        bf16x8 a1 = cvt8(*(const floatx4*)(Ag1 + kt), *(const floatx4*)(Ag1 + kt + 4));
        bf16x8 b0 = cvt8(*(const floatx4*)(Bg0 + kt), *(const floatx4*)(Bg0 + kt + 4));
        bf16x8 b1 = cvt8(*(const floatx4*)(Bg1 + kt), *(const floatx4*)(Bg1 + kt + 4));
        __syncthreads();
        *(bf16x8*)Al0 = a0;
        *(bf16x8*)Al1 = a1;
        *(bf16x8*)Bl0 = b0;
        *(bf16x8*)Bl1 = b1;
        __syncthreads();

        bf16x8 af[4], bfr[4];
#pragma unroll
        for (int i = 0; i < 4; ++i) {
            af[i]  = *(const bf16x8*)&As[(wm * 64 + i * 16 + fm) * TK + fk];
            bfr[i] = *(const bf16x8*)&Bs[(wn * 64 + i * 16 + fm) * TK + fk];
        }
#pragma unroll
        for (int i = 0; i < 4; ++i)
#pragma unroll
            for (int j = 0; j < 4; ++j)
                acc[i][j] = __builtin_amdgcn_mfma_f32_16x16x32_bf16(af[i], bfr[j], acc[i][j], 0, 0, 0);
    }

    const int cn = lane & 15;
    const int cm = (lane >> 4) * 4;
    float bv[4];
#pragma unroll
    for (int j = 0; j < 4; ++j)
        bv[j] = bias[n0 + wn * 64 + j * 16 + cn];
#pragma unroll
    for (int i = 0; i < 4; ++i) {
        const int m = m0 + wm * 64 + i * 16 + cm;
#pragma unroll
        for (int j = 0; j < 4; ++j) {
            const int n = n0 + wn * 64 + j * 16 + cn;
            const size_t base = (size_t)m * Ndim + n;
#pragma unroll
            for (int r = 0; r < 4; ++r)
                C[base + (size_t)r * Ndim] = acc[i][j][r] + bv[j];
        }
    }
}

__global__ __launch_bounds__(256) void lora_rmw(
    const float* __restrict__ x,
    const float* __restrict__ Waq, const float* __restrict__ Wbq,
    const float* __restrict__ Wav, const float* __restrict__ Wbv,
    float* __restrict__ out)
{
    __shared__ float Pq[64][16];
    __shared__ float Pv[64][16];
    const int t  = threadIdx.x;
    const int m0 = blockIdx.x * 64;
    {
        const int row = t >> 2;
        const int r0  = (t & 3) * 4;
        float accq[4] = {0.f, 0.f, 0.f, 0.f};
        float accv[4] = {0.f, 0.f, 0.f, 0.f};
        const float* xr = x + (size_t)(m0 + row) * Kdim;
        for (int d = 0; d < Kdim; d += 4) {
            floatx4 xv = *(const floatx4*)(xr + d);
#pragma unroll
            for (int rr = 0; rr < 4; ++rr) {
                floatx4 wq = *(const floatx4*)(Waq + (size_t)(r0 + rr) * Kdim + d);
                floatx4 wv = *(const floatx4*)(Wav + (size_t)(r0 + rr) * Kdim + d);
#pragma unroll
                for (int e = 0; e < 4; ++e) {
                    accq[rr] += xv[e] * wq[e];
                    accv[rr] += xv[e] * wv[e];
                }
            }
        }
#pragma unroll
        for (int rr = 0; rr < 4; ++rr) {
            Pq[row][r0 + rr] = accq[rr];
            Pv[row][r0 + rr] = accv[rr];
        }
    }
    __syncthreads();
    const int col  = t * 8;
    const bool isq = col < 1024;
    const int nn0  = isq ? col : col - 1024;
    const int n    = isq ? col : col + 1024;
    const float* Wb = isq ? Wbq : Wbv;
    for (int row = 0; row < 64; ++row) {
        const float* P = isq ? Pq[row] : Pv[row];
        const size_t off = (size_t)(m0 + row) * Ndim + n;
        floatx4 o0 = *(const floatx4*)(out + off);
        floatx4 o1 = *(const floatx4*)(out + off + 4);
#pragma unroll
        for (int i = 0; i < 8; ++i) {
            floatx4 w0 = *(const floatx4*)(Wb + (size_t)(nn0 + i) * 16);
            floatx4 w1 = *(const floatx4*)(Wb + (size_t)(nn0 + i) * 16 + 4);
            floatx4 w2 = *(const floatx4*)(Wb + (size_t)(nn0 + i) * 16 + 8);
            floatx4 w3 = *(const floatx4*)(Wb + (size_t)(nn0 + i) * 16 + 12);
            float s = 0.f;
#pragma unroll
            for (int r = 0; r < 4; ++r)
                s += P[r] * w0[r] + P[r + 4] * w1[r] + P[r + 8] * w2[r] + P[r + 12] * w3[r];
            if (i < 4) o0[i] += s; else o1[i - 4] += s;
        }
        *(floatx4*)(out + off)     = o0;
        *(floatx4*)(out + off + 4) = o1;
    }
}

extern "C" void kernel_launch(void* const* d_in, const int* in_sizes, int n_in,
                              void* d_out, int out_size, void* d_ws, size_t ws_size,
                              hipStream_t stream)
{
    (void)in_sizes; (void)n_in; (void)out_size;
    const float* x    = (const float*)d_in[0];
    const float* Wqkv = (const float*)d_in[1];
    const float* bqkv = (const float*)d_in[2];
    const float* Waq  = (const float*)d_in[3];
    const float* Wbq  = (const float*)d_in[4];
    const float* Wav  = (const float*)d_in[5];
    const float* Wbv  = (const float*)d_in[6];
    float* out = (float*)d_out;

    const size_t WEFF_BYTES = (size_t)Ndim * Kdim * sizeof(__hip_bfloat16); // 6.3 MB
    const size_t XB_BYTES   = (size_t)Mdim * Kdim * sizeof(__hip_bfloat16); // 33.5 MB

    if (ws_size >= WEFF_BYTES + XB_BYTES) {
        // fast path: fold LoRA into bf16 W_eff, bf16 x, single MFMA GEMM
        __hip_bfloat16* Weff = (__hip_bfloat16*)d_ws;
        __hip_bfloat16* xb   = (__hip_bfloat16*)((char*)d_ws + WEFF_BYTES);
        build_weff<<<(Ndim * Kdim / 4) / 256, 256, 0, stream>>>(Wqkv, Waq, Wbq, Wav, Wbv, Weff);
        cvt_x<<<(int)(((size_t)Mdim * Kdim / 8) / 256), 256, 0, stream>>>(x, xb);
        gemm_bf16_v6<<<(Mdim / 256) * (Ndim / 256), 512, 0, stream>>>(xb, Weff, bqkv, out);
    } else {
        // fallback: R2 proven path (no scratch)
        gemm_bias_f32<<<(Mdim / 128) * (Ndim / 128), 256, 0, stream>>>(x, Wqkv, bqkv, out);
        lora_rmw<<<Mdim / 64, 256, 0, stream>>>(x, Waq, Wbq, Wav, Wbv, out);
    }
}

// Round 6
// 359.405 us; speedup vs baseline: 1.2104x; 1.0025x over previous
//
#include <hip/hip_runtime.h>
#include <hip/hip_bf16.h>

typedef __bf16 bf16x4 __attribute__((ext_vector_type(4)));
typedef __bf16 bf16x8 __attribute__((ext_vector_type(8)));
typedef float floatx4 __attribute__((ext_vector_type(4)));

#define GLD16(gp, lp) __builtin_amdgcn_global_load_lds(                      \
    (const __attribute__((address_space(1))) void*)(gp),                     \
    (__attribute__((address_space(3))) void*)(lp), 16, 0, 0)

constexpr int Mdim = 16384;   // B*S
constexpr int Ndim = 3072;    // 3*D
constexpr int Kdim = 1024;    // D

static __device__ __forceinline__ bf16x8 cvt8(floatx4 lo, floatx4 hi) {
    bf16x8 r;
#pragma unroll
    for (int e = 0; e < 4; ++e) { r[e] = (__bf16)lo[e]; r[e + 4] = (__bf16)hi[e]; }
    return r;
}

// ===========================================================================
// FAST PATH (requires ws_size >= 40 MB)
// ===========================================================================

// --- prep (fused): W_eff = W_qkv + LoRA fold -> bf16;  x fp32 -> bf16 ------
__global__ __launch_bounds__(256) void prep(
    const float* __restrict__ x,
    const float* __restrict__ Wqkv,   // 3072 x 1024
    const float* __restrict__ Waq,    // 16 x 1024
    const float* __restrict__ Wbq,    // 1024 x 16
    const float* __restrict__ Wav,    // 16 x 1024
    const float* __restrict__ Wbv,    // 1024 x 16
    __hip_bfloat16* __restrict__ Weff,
    __hip_bfloat16* __restrict__ xb)
{
    if (blockIdx.x < 3072) {
        // ---- W_eff part ----
        const int idx = (blockIdx.x * 256 + threadIdx.x) * 4;  // e*1024 + d
        const int e = idx >> 10;
        const int d = idx & 1023;
        floatx4 v = *(const floatx4*)(Wqkv + idx);
        if (e < 1024) {
#pragma unroll
            for (int r = 0; r < 16; ++r) {
                const float wb = Wbq[e * 16 + r];
                floatx4 wa = *(const floatx4*)(Waq + r * 1024 + d);
#pragma unroll
                for (int q = 0; q < 4; ++q) v[q] += wb * wa[q];
            }
        } else if (e >= 2048) {
            const int e2 = e - 2048;
#pragma unroll
            for (int r = 0; r < 16; ++r) {
                const float wb = Wbv[e2 * 16 + r];
                floatx4 wa = *(const floatx4*)(Wav + r * 1024 + d);
#pragma unroll
                for (int q = 0; q < 4; ++q) v[q] += wb * wa[q];
            }
        }
        bf16x4 o;
#pragma unroll
        for (int q = 0; q < 4; ++q) o[q] = (__bf16)v[q];
        *(bf16x4*)(Weff + idx) = o;
    } else {
        // ---- cvt_x part ----
        const size_t idx = ((size_t)(blockIdx.x - 3072) * 256 + threadIdx.x) * 8;
        bf16x8 r = cvt8(*(const floatx4*)(x + idx), *(const floatx4*)(x + idx + 4));
        *(bf16x8*)(xb + idx) = r;
    }
}

// --- main GEMM v7: persistent 256 blocks (1/CU exact), 3 n-tiles/block, ----
// continuous 48-step virtual-K stream. Per K-tile: v6's verified 4-phase
// schedule (1 half-tile staged/phase, vmcnt(6) once/K-tile, 3 barriers,
// both-sides XOR swizzle = 0 conflicts, setprio on MFMA). Tile boundaries:
// acc store-burst enters the vmem queue and is absorbed by the next tile's
// vmcnt(6) (in-order retire) -- no prologue restart, no round serialization.
__global__ __launch_bounds__(512, 2) void gemm_bf16_v7(
    const __hip_bfloat16* __restrict__ A,     // M x K bf16
    const __hip_bfloat16* __restrict__ Bw,    // N x K bf16 (W_eff)
    const float* __restrict__ bias,           // N fp32
    float* __restrict__ C)                    // M x N fp32
{
    constexpr int NT  = Kdim / 64;            // 16 K-tiles per output tile
    constexpr int TPB = 3;                    // n-tiles per block
    constexpr int NVK = NT * TPB;             // 48 virtual K-tiles
    // buf b at b*65536; A half h at +h*16384; B at +32768+h*16384. 128 KiB.
    __shared__ __align__(16) char smem[131072];

    const int t    = threadIdx.x;
    const int wid  = t >> 6;
    const int lane = t & 63;
    const int wm   = wid >> 2;        // 2 wave-rows, 128 out-rows each
    const int wn   = wid & 3;         // 4 wave-cols, 64 out-cols each

    // 256 blocks; XCD swizzle: each XCD gets 32 contiguous bids (8 m-panels).
    const int bid  = (blockIdx.x & 7) * 32 + (blockIdx.x >> 3);
    const int m0   = (bid >> 2) * 256;        // 64 m-tiles
    const int n_b  = (bid & 3) * TPB * 256;   // first of 3 n-tiles

    // staging: linear LDS dest (t*16), swizzle via pre-permuted global col.
    const int srow0 = t >> 3;                              // 0..63
    const int scb   = ((t & 7) * 16) ^ ((srow0 & 7) << 4); // swizzled col-byte
    const __hip_bfloat16* Ag  = A  + (size_t)(m0 + srow0) * Kdim + (scb >> 1);
    const __hip_bfloat16* Bg0 = Bw + (size_t)srow0 * Kdim + (scb >> 1);

    // stage half h of matrix mat (0=A,1=B) for virtual K-tile vk_ into buf b_
#define STG(mat, h, vk_, b_) do {                                              \
    const int _vk = (vk_);                                                     \
    const __hip_bfloat16* _g;                                                  \
    if (mat) _g = Bg0 + (size_t)(n_b + (_vk >> 4) * 256 + (h) * 128) * Kdim    \
                  + (_vk & 15) * 64;                                           \
    else     _g = Ag + (size_t)((h) * 128) * Kdim + (_vk & 15) * 64;           \
    char* _l = smem + (b_) * 65536 + (mat) * 32768 + (h) * 16384 + t * 16;     \
    GLD16(_g,                     _l);                                         \
    GLD16(_g + (size_t)64 * Kdim, _l + 8192);                                  \
} while (0)

    // frag-read geometry: row stride 128 B; frag rows ≡ fm (mod 8) always.
    const int fm  = lane & 15;
    const int fk2 = (lane >> 4) * 16;
    const int fx  = (fm & 7) << 4;
    const int cb0 = fk2 ^ fx;             // k 0..31
    const int cb1 = (64 + fk2) ^ fx;      // k 32..63
    const int cn  = lane & 15;
    const int cm  = (lane >> 4) * 4;

    floatx4 acc[8][4];
#pragma unroll
    for (int i = 0; i < 8; ++i)
#pragma unroll
        for (int j = 0; j < 4; ++j)
            acc[i][j] = (floatx4){0.f, 0.f, 0.f, 0.f};

#define MFMA_Q(mq, nq, BQ)                                                     \
    __builtin_amdgcn_s_setprio(1);                                             \
    _Pragma("unroll")                                                          \
    for (int i = 0; i < 4; ++i)                                                \
        _Pragma("unroll")                                                      \
        for (int j = 0; j < 2; ++j) {                                          \
            acc[(mq) * 4 + i][(nq) * 2 + j] =                                  \
                __builtin_amdgcn_mfma_f32_16x16x32_bf16(                       \
                    aq[i][0], BQ[j][0], acc[(mq) * 4 + i][(nq) * 2 + j], 0,0,0);\
            acc[(mq) * 4 + i][(nq) * 2 + j] =                                  \
                __builtin_amdgcn_mfma_f32_16x16x32_bf16(                       \
                    aq[i][1], BQ[j][1], acc[(mq) * 4 + i][(nq) * 2 + j], 0,0,0);\
        }                                                                      \
    __builtin_amdgcn_s_setprio(0);

#define STORE_TILE(N0_) do {                                                   \
    _Pragma("unroll")                                                          \
    for (int mi = 0; mi < 8; ++mi) {                                           \
        const int m = m0 + wm * 128 + mi * 16 + cm;                            \
        _Pragma("unroll")                                                      \
        for (int ni = 0; ni < 4; ++ni) {                                       \
            const int n = (N0_) + wn * 64 + ni * 16 + cn;                      \
            const size_t base = (size_t)m * Ndim + n;                          \
            _Pragma("unroll")                                                  \
            for (int r = 0; r < 4; ++r)                                        \
                C[base + (size_t)r * Ndim] = acc[mi][ni][r] + bv[ni];          \
        }                                                                      \
    }                                                                          \
} while (0)

    int n0 = n_b;
    float bv[4];
#pragma unroll
    for (int j = 0; j < 4; ++j)
        bv[j] = bias[n0 + wn * 64 + j * 16 + cn];

    // prologue: queue = A0(0) A1(0) B0(0) B1(0) B0(1) A0(1)  [12 ops]
    STG(0, 0, 0, 0); STG(0, 1, 0, 0); STG(1, 0, 0, 0); STG(1, 1, 0, 0);
    STG(1, 0, 1, 1); STG(0, 0, 1, 1);

    bf16x8 aq[4][2], bq0[2][2], bq1[2][2];

#pragma unroll 1
    for (int tile = 0; tile < TPB; ++tile) {
        for (int kt = 0; kt < NT; ++kt) {
            const int vkt = tile * NT + kt;
            const int b   = vkt & 1;
            const char* Ab = smem + b * 65536;
            const char* Bb = Ab + 32768;

            // ---- P0: quad(0,0) ----
            if (vkt + 1 < NVK) {
                STG(0, 1, vkt + 1, b ^ 1);            // A-h1(t+1)
                asm volatile("s_waitcnt vmcnt(6)" ::: "memory");  // tile t landed
            } else {
                asm volatile("s_waitcnt vmcnt(0)" ::: "memory");
            }
            __builtin_amdgcn_s_barrier();             // (a): buffer visible
            __builtin_amdgcn_sched_barrier(0x8);      // pin loads; MFMA may cross
#pragma unroll
            for (int i = 0; i < 4; ++i) {
                const char* ar = Ab + (wm * 128 + i * 16 + fm) * 128;
                aq[i][0] = *(const bf16x8*)(ar + cb0);
                aq[i][1] = *(const bf16x8*)(ar + cb1);
            }
#pragma unroll
            for (int j = 0; j < 2; ++j) {
                const char* br = Bb + (wn * 64 + j * 16 + fm) * 128;
                bq0[j][0] = *(const bf16x8*)(br + cb0);
                bq0[j][1] = *(const bf16x8*)(br + cb1);
            }
            MFMA_Q(0, 0, bq0)

            // ---- P1: quad(0,1) ----
#pragma unroll
            for (int j = 0; j < 2; ++j) {
                const char* br = Bb + (wn * 64 + 32 + j * 16 + fm) * 128;
                bq1[j][0] = *(const bf16x8*)(br + cb0);
                bq1[j][1] = *(const bf16x8*)(br + cb1);
            }
            if (vkt + 1 < NVK) STG(1, 1, vkt + 1, b ^ 1);   // B-h1(t+1)
            MFMA_Q(0, 1, bq1)
            __builtin_amdgcn_s_barrier();             // (b): B(t)/aq0 reads done
            __builtin_amdgcn_sched_barrier(0x108);

            // ---- P2: quad(1,0) ----
#pragma unroll
            for (int i = 0; i < 4; ++i) {
                const char* ar = Ab + (wm * 128 + 64 + i * 16 + fm) * 128;
                aq[i][0] = *(const bf16x8*)(ar + cb0);
                aq[i][1] = *(const bf16x8*)(ar + cb1);
            }
            if (vkt + 2 < NVK) STG(1, 0, vkt + 2, b); // B-h0(t+2), same buf
            MFMA_Q(1, 0, bq0)
            __builtin_amdgcn_s_barrier();             // (c): aq1 reads done
            __builtin_amdgcn_sched_barrier(0x108);

            // ---- P3: quad(1,1) ---- (register-only; overlaps next P0)
            if (vkt + 2 < NVK) STG(0, 0, vkt + 2, b); // A-h0(t+2), same buf
            MFMA_Q(1, 1, bq1)
        }
        // ---- tile boundary: store acc burst (enters vmem queue; absorbed
        // by next tile's vmcnt(6)); reset acc; advance n0 and bias ----
        if (tile + 1 < TPB) {
            STORE_TILE(n0);
#pragma unroll
            for (int i = 0; i < 8; ++i)
#pragma unroll
                for (int j = 0; j < 4; ++j)
                    acc[i][j] = (floatx4){0.f, 0.f, 0.f, 0.f};
            n0 += 256;
#pragma unroll
            for (int j = 0; j < 4; ++j)
                bv[j] = bias[n0 + wn * 64 + j * 16 + cn];
        }
    }

    // final tile epilogue
    STORE_TILE(n0);
#undef STG
#undef MFMA_Q
#undef STORE_TILE
}

// ===========================================================================
// FALLBACK PATH (R2, proven): used only if ws_size < 40 MB
// ===========================================================================

__global__ __launch_bounds__(256, 2) void gemm_bias_f32(
    const float* __restrict__ A, const float* __restrict__ Bw,
    const float* __restrict__ bias, float* __restrict__ C)
{
    constexpr int TK = 32;
    __shared__ __hip_bfloat16 As[128 * TK];
    __shared__ __hip_bfloat16 Bs[128 * TK];

    const int t    = threadIdx.x;
    const int wave = t >> 6;
    const int lane = t & 63;
    const int bx   = blockIdx.x % (Ndim / 128);
    const int by   = blockIdx.x / (Ndim / 128);
    const int m0   = by * 128;
    const int n0   = bx * 128;
    const int wm   = wave >> 1;
    const int wn   = wave & 1;
    const int srow = wave * 16 + (lane >> 2);
    const int scol = (lane & 3) * 8;

    const float* Ag0 = A  + (size_t)(m0 + srow) * Kdim + scol;
    const float* Ag1 = Ag0 + (size_t)64 * Kdim;
    const float* Bg0 = Bw + (size_t)(n0 + srow) * Kdim + scol;
    const float* Bg1 = Bg0 + (size_t)64 * Kdim;

    __hip_bfloat16* Al0 = &As[srow * TK + scol];
    __hip_bfloat16* Al1 = &As[(srow + 64) * TK + scol];
    __hip_bfloat16* Bl0 = &Bs[srow * TK + scol];
    __hip_bfloat16* Bl1 = &Bs[(srow + 64) * TK + scol];

    const int fm = lane & 15;
    const int fk = (lane >> 4) * 8;

    floatx4 acc[4][4];
#pragma unroll
    for (int i = 0; i < 4; ++i)
#pragma unroll
        for (int j = 0; j < 4; ++j)
            acc[i][j] = (floatx4){0.f, 0.f, 0.f, 0.f};

    for (int kt = 0; kt < Kdim; kt += TK) {
        bf16x8 a0 = cvt8(*(const floatx4*)(Ag0 + kt), *(const floatx4*)(Ag0 + kt + 4));
        bf16x8 a1 = cvt8(*(const floatx4*)(Ag1 + kt), *(const floatx4*)(Ag1 + kt + 4));
        bf16x8 b0 = cvt8(*(const floatx4*)(Bg0 + kt), *(const floatx4*)(Bg0 + kt + 4));
        bf16x8 b1 = cvt8(*(const floatx4*)(Bg1 + kt), *(const floatx4*)(Bg1 + kt + 4));
        __syncthreads();
        *(bf16x8*)Al0 = a0;
        *(bf16x8*)Al1 = a1;
        *(bf16x8*)Bl0 = b0;
        *(bf16x8*)Bl1 = b1;
        __syncthreads();

        bf16x8 af[4], bfr[4];
#pragma unroll
        for (int i = 0; i < 4; ++i) {
            af[i]  = *(const bf16x8*)&As[(wm * 64 + i * 16 + fm) * TK + fk];
            bfr[i] = *(const bf16x8*)&Bs[(wn * 64 + i * 16 + fm) * TK + fk];
        }
#pragma unroll
        for (int i = 0; i < 4; ++i)
#pragma unroll
            for (int j = 0; j < 4; ++j)
                acc[i][j] = __builtin_amdgcn_mfma_f32_16x16x32_bf16(af[i], bfr[j], acc[i][j], 0, 0, 0);
    }

    const int cn = lane & 15;
    const int cm = (lane >> 4) * 4;
    float bv[4];
#pragma unroll
    for (int j = 0; j < 4; ++j)
        bv[j] = bias[n0 + wn * 64 + j * 16 + cn];
#pragma unroll
    for (int i = 0; i < 4; ++i) {
        const int m = m0 + wm * 64 + i * 16 + cm;
#pragma unroll
        for (int j = 0; j < 4; ++j) {
            const int n = n0 + wn * 64 + j * 16 + cn;
            const size_t base = (size_t)m * Ndim + n;
#pragma unroll
            for (int r = 0; r < 4; ++r)
                C[base + (size_t)r * Ndim] = acc[i][j][r] + bv[j];
        }
    }
}

__global__ __launch_bounds__(256) void lora_rmw(
    const float* __restrict__ x,
    const float* __restrict__ Waq, const float* __restrict__ Wbq,
    const float* __restrict__ Wav, const float* __restrict__ Wbv,
    float* __restrict__ out)
{
    __shared__ float Pq[64][16];
    __shared__ float Pv[64][16];
    const int t  = threadIdx.x;
    const int m0 = blockIdx.x * 64;
    {
        const int row = t >> 2;
        const int r0  = (t & 3) * 4;
        float accq[4] = {0.f, 0.f, 0.f, 0.f};
        float accv[4] = {0.f, 0.f, 0.f, 0.f};
        const float* xr = x + (size_t)(m0 + row) * Kdim;
        for (int d = 0; d < Kdim; d += 4) {
            floatx4 xv = *(const floatx4*)(xr + d);
#pragma unroll
            for (int rr = 0; rr < 4; ++rr) {
                floatx4 wq = *(const floatx4*)(Waq + (size_t)(r0 + rr) * Kdim + d);
                floatx4 wv = *(const floatx4*)(Wav + (size_t)(r0 + rr) * Kdim + d);
#pragma unroll
                for (int e = 0; e < 4; ++e) {
                    accq[rr] += xv[e] * wq[e];
                    accv[rr] += xv[e] * wv[e];
                }
            }
        }
#pragma unroll
        for (int rr = 0; rr < 4; ++rr) {
            Pq[row][r0 + rr] = accq[rr];
            Pv[row][r0 + rr] = accv[rr];
        }
    }
    __syncthreads();
    const int col  = t * 8;
    const bool isq = col < 1024;
    const int nn0  = isq ? col : col - 1024;
    const int n    = isq ? col : col + 1024;
    const float* Wb = isq ? Wbq : Wbv;
    for (int row = 0; row < 64; ++row) {
        const float* P = isq ? Pq[row] : Pv[row];
        const size_t off = (size_t)(m0 + row) * Ndim + n;
        floatx4 o0 = *(const floatx4*)(out + off);
        floatx4 o1 = *(const floatx4*)(out + off + 4);
#pragma unroll
        for (int i = 0; i < 8; ++i) {
            floatx4 w0 = *(const floatx4*)(Wb + (size_t)(nn0 + i) * 16);
            floatx4 w1 = *(const floatx4*)(Wb + (size_t)(nn0 + i) * 16 + 4);
            floatx4 w2 = *(const floatx4*)(Wb + (size_t)(nn0 + i) * 16 + 8);
            floatx4 w3 = *(const floatx4*)(Wb + (size_t)(nn0 + i) * 16 + 12);
            float s = 0.f;
#pragma unroll
            for (int r = 0; r < 4; ++r)
                s += P[r] * w0[r] + P[r + 4] * w1[r] + P[r + 8] * w2[r] + P[r + 12] * w3[r];
            if (i < 4) o0[i] += s; else o1[i - 4] += s;
        }
        *(floatx4*)(out + off)     = o0;
        *(floatx4*)(out + off + 4) = o1;
    }
}

extern "C" void kernel_launch(void* const* d_in, const int* in_sizes, int n_in,
                              void* d_out, int out_size, void* d_ws, size_t ws_size,
                              hipStream_t stream)
{
    (void)in_sizes; (void)n_in; (void)out_size;
    const float* x    = (const float*)d_in[0];
    const float* Wqkv = (const float*)d_in[1];
    const float* bqkv = (const float*)d_in[2];
    const float* Waq  = (const float*)d_in[3];
    const float* Wbq  = (const float*)d_in[4];
    const float* Wav  = (const float*)d_in[5];
    const float* Wbv  = (const float*)d_in[6];
    float* out = (float*)d_out;

    const size_t WEFF_BYTES = (size_t)Ndim * Kdim * sizeof(__hip_bfloat16); // 6.3 MB
    const size_t XB_BYTES   = (size_t)Mdim * Kdim * sizeof(__hip_bfloat16); // 33.5 MB

    if (ws_size >= WEFF_BYTES + XB_BYTES) {
        // fast path: fold LoRA into bf16 W_eff, bf16 x, single MFMA GEMM
        __hip_bfloat16* Weff = (__hip_bfloat16*)d_ws;
        __hip_bfloat16* xb   = (__hip_bfloat16*)((char*)d_ws + WEFF_BYTES);
        prep<<<3072 + 8192, 256, 0, stream>>>(x, Wqkv, Waq, Wbq, Wav, Wbv, Weff, xb);
        gemm_bf16_v7<<<256, 512, 0, stream>>>(xb, Weff, bqkv, out);
    } else {
        // fallback: R2 proven path (no scratch)
        gemm_bias_f32<<<(Mdim / 128) * (Ndim / 128), 256, 0, stream>>>(x, Wqkv, bqkv, out);
        lora_rmw<<<Mdim / 64, 256, 0, stream>>>(x, Waq, Wbq, Wav, Wbv, out);
    }
}